// Round 2
// baseline (3202.837 us; speedup 1.0000x reference)
//
#include <hip/hip_runtime.h>
#include <hip/hip_bf16.h>

// Swin block, B=32 H=W=56 C=128, ws=7 (N=49), nh=4 (hd=32), shift=3, MLP hid=512.
// ALL float tensors are fp32 (reference dtype); rel_idx is int32.
// roll(-3) window gather and roll(+3) reverse hit the SAME token -> fused.
// x2 intermediate lives in d_out (attn writes all tokens; mlp reads only its
// own tokens into LDS before overwriting them -> no hazard, no d_ws needed).

#define TOK    100352   // 32*3136
#define NWIN   2048     // 32 * 8 * 8

__device__ __forceinline__ float bl(unsigned u) { return __uint_as_float(u << 16); }
__device__ __forceinline__ float bh(unsigned u) { return __uint_as_float(u & 0xffff0000u); }

// w: 8 fp32 (2x float4) dot h: 8 bf16 (uint4)
__device__ __forceinline__ float dot8_fb(float4 wa, float4 wb, uint4 h) {
  return wa.x*bl(h.x) + wa.y*bh(h.x) + wa.z*bl(h.y) + wa.w*bh(h.y)
       + wb.x*bl(h.z) + wb.y*bh(h.z) + wb.z*bl(h.w) + wb.w*bh(h.w);
}
__device__ __forceinline__ float dot4_ff(float4 a, float4 b) {
  return a.x*b.x + a.y*b.y + a.z*b.z + a.w*b.w;
}

// ---------------- Kernel A: LN1 + window attention + proj + shortcut ----------------
__global__ __launch_bounds__(256) void attn_kernel(
    const float* __restrict__ x,
    const float* __restrict__ n1g, const float* __restrict__ n1b,
    const float* __restrict__ qkvw, const float* __restrict__ qkvb,
    const float* __restrict__ tab,  const int* __restrict__ ridx,
    const float* __restrict__ projw, const float* __restrict__ projb,
    float* __restrict__ x2)
{
  // pad rows: hbuf stride 136 (272B), qkv row stride 40 (80B) -> 16B aligned,
  // bank groups spread 8-ways for per-lane-row access patterns.
  __shared__ alignas(16) __hip_bfloat16 hbuf[49][136];          // h tile; reused as o tile
  __shared__ alignas(16) __hip_bfloat16 qkvbuf[3][4][49][40];   // [q/k/v][head][n][d(32 of 40)]
  const int tid  = threadIdx.x;
  const int wave = tid >> 6, lane = tid & 63;
  const int wb = blockIdx.x;
  const int b = wb >> 6, wi = (wb >> 3) & 7, wj = wb & 7;

  // ---- phase 1: LN1 over source rows (roll -3), window tile -> LDS (bf16) ----
  for (int n = wave; n < 49; n += 4) {
    int r = n / 7, c = n - r * 7;
    int si = wi*7 + r + 3; if (si >= 56) si -= 56;
    int sj = wj*7 + c + 3; if (sj >= 56) sj -= 56;
    const float* xr = x + (b*3136 + si*56 + sj) * 128;
    float v0 = xr[lane];
    float v1 = xr[lane + 64];
    float s = v0 + v1, sq = v0*v0 + v1*v1;
    #pragma unroll
    for (int off = 32; off > 0; off >>= 1) {
      s  += __shfl_xor(s,  off);
      sq += __shfl_xor(sq, off);
    }
    float mean = s * 0.0078125f;
    float var  = sq * 0.0078125f - mean*mean;
    float rstd = rsqrtf(var + 1e-5f);
    hbuf[n][lane]    = __float2bfloat16((v0-mean)*rstd*n1g[lane]    + n1b[lane]);
    hbuf[n][lane+64] = __float2bfloat16((v1-mean)*rstd*n1g[lane+64] + n1b[lane+64]);
  }
  __syncthreads();

  // ---- phase 2: qkv = h @ qkv_w^T + b ; q *= scale. lanes share weight row m ----
  for (int idx = tid; idx < 49*384; idx += 256) {
    int m = idx / 49, n = idx - m*49;
    const float4* w4 = (const float4*)(qkvw + m*128);
    const uint4*  h4 = (const uint4*)(hbuf[n]);
    float acc = 0.f;
    #pragma unroll
    for (int k = 0; k < 16; ++k) acc += dot8_fb(w4[2*k], w4[2*k+1], h4[k]);
    acc += qkvb[m];
    int which = m >> 7, mm = m & 127, hh = mm >> 5, d = mm & 31;
    if (which == 0) acc *= 0.17677669529663687f;  // 1/sqrt(32)
    qkvbuf[which][hh][n][d] = __float2bfloat16(acc);
  }
  __syncthreads();

  // ---- phase 3: attention. wave = head, lane = query row (49 active) ----
  if (lane < 49) {
    const int h = wave;
    float qd[32];
    const uint4* q4 = (const uint4*)(&qkvbuf[0][h][lane][0]);
    #pragma unroll
    for (int i = 0; i < 4; ++i) {
      uint4 u = q4[i];
      qd[i*8+0]=bl(u.x); qd[i*8+1]=bh(u.x); qd[i*8+2]=bl(u.y); qd[i*8+3]=bh(u.y);
      qd[i*8+4]=bl(u.z); qd[i*8+5]=bh(u.z); qd[i*8+6]=bl(u.w); qd[i*8+7]=bh(u.w);
    }
    float p[49];
    float mx = -3.0e38f;
    #pragma unroll
    for (int m = 0; m < 49; ++m) {
      const uint4* k4 = (const uint4*)(&qkvbuf[1][h][m][0]);
      float s = 0.f;
      #pragma unroll
      for (int i = 0; i < 4; ++i) {
        uint4 u = k4[i];
        s += qd[i*8+0]*bl(u.x)+qd[i*8+1]*bh(u.x)+qd[i*8+2]*bl(u.y)+qd[i*8+3]*bh(u.y)
           + qd[i*8+4]*bl(u.z)+qd[i*8+5]*bh(u.z)+qd[i*8+6]*bl(u.w)+qd[i*8+7]*bh(u.w);
      }
      s += tab[ridx[lane*49 + m]*4 + h];
      p[m] = s;
      mx = fmaxf(mx, s);
    }
    float sum = 0.f;
    #pragma unroll
    for (int m = 0; m < 49; ++m) { p[m] = __expf(p[m] - mx); sum += p[m]; }
    float inv = 1.f / sum;
    float o[32];
    #pragma unroll
    for (int d = 0; d < 32; ++d) o[d] = 0.f;
    #pragma unroll
    for (int m = 0; m < 49; ++m) {
      const uint4* v4 = (const uint4*)(&qkvbuf[2][h][m][0]);
      float pm = p[m];
      #pragma unroll
      for (int i = 0; i < 4; ++i) {
        uint4 u = v4[i];
        o[i*8+0]+=pm*bl(u.x); o[i*8+1]+=pm*bh(u.x); o[i*8+2]+=pm*bl(u.y); o[i*8+3]+=pm*bh(u.y);
        o[i*8+4]+=pm*bl(u.z); o[i*8+5]+=pm*bh(u.z); o[i*8+6]+=pm*bl(u.w); o[i*8+7]+=pm*bh(u.w);
      }
    }
    // hbuf reads are done (phase-2 synced); safe to overwrite as o tile
    #pragma unroll
    for (int d = 0; d < 32; ++d)
      hbuf[lane][h*32 + d] = __float2bfloat16(o[d] * inv);
  }
  __syncthreads();

  // ---- phase 4: proj + shortcut, scatter back (roll +3 == same token) ----
  for (int idx = tid; idx < 49*128; idx += 256) {
    int ch = idx / 49, n = idx - ch*49;   // lanes share proj row ch
    const uint4*  o4 = (const uint4*)(hbuf[n]);
    const float4* w4 = (const float4*)(projw + ch*128);
    float acc = 0.f;
    #pragma unroll
    for (int k = 0; k < 16; ++k) acc += dot8_fb(w4[2*k], w4[2*k+1], o4[k]);
    acc += projb[ch];
    int r = n / 7, c = n - r * 7;
    int si = wi*7 + r + 3; if (si >= 56) si -= 56;
    int sj = wj*7 + c + 3; if (sj >= 56) sj -= 56;
    int tok = b*3136 + si*56 + sj;
    x2[tok*128 + ch] = acc + x[tok*128 + ch];
  }
}

// ---------------- Kernel B: LN2 + MLP(gelu) + residual (fully fp32) ----------------
__global__ __launch_bounds__(256) void mlp_kernel(
    const float* __restrict__ x2,
    const float* __restrict__ n2g, const float* __restrict__ n2b,
    const float* __restrict__ w1, const float* __restrict__ b1,
    const float* __restrict__ w2, const float* __restrict__ b2,
    float* __restrict__ out)
{
  __shared__ alignas(16) float ln2s[8][132];   // pad -> conflict-free broadcast
  __shared__ alignas(16) float x2s[8][128];
  __shared__ alignas(16) float h2s[8][516];
  const int tid = threadIdx.x, wave = tid >> 6, lane = tid & 63;
  const int tok0 = blockIdx.x * 8;

  // LN2 for 8 tokens (wave per token, 2 ch/lane); also snapshot x2 rows to LDS
  for (int t = wave; t < 8; t += 4) {
    const float* xr = x2 + (tok0 + t)*128;
    float v0 = xr[lane];
    float v1 = xr[lane + 64];
    float s = v0 + v1, sq = v0*v0 + v1*v1;
    #pragma unroll
    for (int off = 32; off > 0; off >>= 1) {
      s  += __shfl_xor(s,  off);
      sq += __shfl_xor(sq, off);
    }
    float mean = s * 0.0078125f;
    float var  = sq * 0.0078125f - mean*mean;
    float rstd = rsqrtf(var + 1e-5f);
    x2s[t][lane] = v0; x2s[t][lane+64] = v1;
    ln2s[t][lane]    = (v0-mean)*rstd*n2g[lane]    + n2b[lane];
    ln2s[t][lane+64] = (v1-mean)*rstd*n2g[lane+64] + n2b[lane+64];
  }
  __syncthreads();

  // MLP1 + exact GELU: lanes share w1 row j (8 lanes each)
  for (int it = 0; it < 16; ++it) {
    int oi = it*256 + tid;
    int j = oi >> 3, t = oi & 7;
    const float4* w4 = (const float4*)(w1 + j*128);
    const float4* lf = (const float4*)(ln2s[t]);
    float acc = 0.f;
    #pragma unroll
    for (int k = 0; k < 32; ++k) acc += dot4_ff(w4[k], lf[k]);
    acc += b1[j];
    h2s[t][j] = 0.5f * acc * (1.f + erff(acc * 0.70710678118654752f));
  }
  __syncthreads();

  // MLP2 + residual: lanes share w2 row ch (8 lanes each)
  for (int it = 0; it < 4; ++it) {
    int oi = it*256 + tid;
    int ch = oi >> 3, t = oi & 7;
    const float4* w4 = (const float4*)(w2 + ch*512);
    const float4* hf = (const float4*)(h2s[t]);
    float acc = 0.f;
    #pragma unroll 16
    for (int k = 0; k < 128; ++k) acc += dot4_ff(w4[k], hf[k]);
    acc += b2[ch] + x2s[t][ch];
    out[(tok0 + t)*128 + ch] = acc;
  }
}

extern "C" void kernel_launch(void* const* d_in, const int* in_sizes, int n_in,
                              void* d_out, int out_size, void* d_ws, size_t ws_size,
                              hipStream_t stream) {
  const float* x     = (const float*)d_in[0];
  // d_in[1] = H (56), d_in[2] = W (56) — fixed, hardcoded
  const float* n1g   = (const float*)d_in[3];
  const float* n1b   = (const float*)d_in[4];
  const float* qkvw  = (const float*)d_in[5];
  const float* qkvb  = (const float*)d_in[6];
  const float* tab   = (const float*)d_in[7];
  const int*   ridx  = (const int*)d_in[8];
  const float* projw = (const float*)d_in[9];
  const float* projb = (const float*)d_in[10];
  const float* n2g   = (const float*)d_in[11];
  const float* n2b   = (const float*)d_in[12];
  const float* w1    = (const float*)d_in[13];
  const float* b1    = (const float*)d_in[14];
  const float* w2    = (const float*)d_in[15];
  const float* b2    = (const float*)d_in[16];
  float* outp = (float*)d_out;

  // x2 lives in d_out: attn writes every token; mlp reads its own 8 tokens
  // into LDS before overwriting them.
  hipLaunchKernelGGL(attn_kernel, dim3(NWIN), dim3(256), 0, stream,
                     x, n1g, n1b, qkvw, qkvb, tab, ridx, projw, projb, outp);
  hipLaunchKernelGGL(mlp_kernel, dim3(TOK/8), dim3(256), 0, stream,
                     outp, n2g, n2b, w1, b1, w2, b2, outp);
}

// Round 3
// 642.098 us; speedup vs baseline: 4.9881x; 4.9881x over previous
//
#include <hip/hip_runtime.h>
#include <hip/hip_bf16.h>

// Swin block, B=32 H=W=56 C=128, ws=7 (N=49), nh=4 (hd=32), shift=3, MLP hid=512.
// fp32 in/out. All GEMMs via mfma_f32_16x16x32_bf16 (fp32 accum).
// roll(-3) gather and roll(+3) reverse hit the SAME token -> fused windows.
// d_ws: bf16 weight copies + pre-gathered rel bias. x2 lives in d_out.

#define TOK  100352
#define NWIN 2048

typedef short short8 __attribute__((ext_vector_type(8)));
typedef float f32x4  __attribute__((ext_vector_type(4)));

// d_ws layout (bf16 elements unless noted)
#define QKVW_OFF 0        // 384*128
#define PROJW_OFF 49152   // 128*128
#define W1_OFF   65536    // 512*128
#define W2_OFF   131072   // 128*512
#define BIAS_BYTE_OFF 393216  // [4][49][49] fp32

// ---------------- pre-pass: weights -> bf16, rel-bias gather ----------------
__global__ __launch_bounds__(256) void conv_kernel(
    const float* __restrict__ qkvw, const float* __restrict__ projw,
    const float* __restrict__ w1,   const float* __restrict__ w2,
    const float* __restrict__ tab,  const int* __restrict__ ridx,
    __hip_bfloat16* __restrict__ wsb, float* __restrict__ biasf)
{
  int idx = blockIdx.x * 256 + threadIdx.x;
  if (idx < 49152)       wsb[QKVW_OFF + idx]           = __float2bfloat16(qkvw[idx]);
  else if (idx < 65536)  wsb[PROJW_OFF + idx - 49152]  = __float2bfloat16(projw[idx - 49152]);
  else if (idx < 131072) wsb[W1_OFF + idx - 65536]     = __float2bfloat16(w1[idx - 65536]);
  else if (idx < 196608) wsb[W2_OFF + idx - 131072]    = __float2bfloat16(w2[idx - 131072]);
  else if (idx < 206212) {
    int i = idx - 196608;
    int h = i / 2401, rem = i - h * 2401;       // rem = n*49 + m
    biasf[i] = tab[ridx[rem] * 4 + h];
  }
}

__device__ __forceinline__ float bl(unsigned u) { return __uint_as_float(u << 16); }
__device__ __forceinline__ float bh(unsigned u) { return __uint_as_float(u & 0xffff0000u); }

// ---------------- Kernel A: LN1 + window attention + proj + shortcut ----------------
__global__ __launch_bounds__(256) void attn_kernel(
    const float* __restrict__ x,
    const float* __restrict__ n1g, const float* __restrict__ n1b,
    const __hip_bfloat16* __restrict__ qkvwb, const float* __restrict__ qkvb,
    const float* __restrict__ biasf,
    const __hip_bfloat16* __restrict__ projwb, const float* __restrict__ projb,
    float* __restrict__ x2)
{
  __shared__ alignas(16) __hip_bfloat16 hbuf[64][136];          // h tile / o tile (rows 49+ unused)
  __shared__ alignas(16) __hip_bfloat16 qkvbuf[3][4][49][40];   // [q/k/v][head][tok][d]
  const int tid = threadIdx.x, wave = tid >> 6, lane = tid & 63;
  const int l15 = lane & 15, quad = lane >> 4;
  const int wb = blockIdx.x;
  const int b = wb >> 6, wi = (wb >> 3) & 7, wj = wb & 7;

  // ---- phase 1: LN1 over source rows (roll -3) -> hbuf bf16 ----
  for (int n = wave; n < 49; n += 4) {
    int r = n / 7, c = n - r * 7;
    int si = wi*7 + r + 3; if (si >= 56) si -= 56;
    int sj = wj*7 + c + 3; if (sj >= 56) sj -= 56;
    const float* xr = x + (b*3136 + si*56 + sj) * 128;
    float v0 = xr[lane], v1 = xr[lane + 64];
    float s = v0 + v1, sq = v0*v0 + v1*v1;
    #pragma unroll
    for (int off = 32; off > 0; off >>= 1) {
      s  += __shfl_xor(s,  off);
      sq += __shfl_xor(sq, off);
    }
    float mean = s * 0.0078125f;
    float var  = sq * 0.0078125f - mean*mean;
    float rstd = rsqrtf(var + 1e-5f);
    hbuf[n][lane]    = __float2bfloat16((v0-mean)*rstd*n1g[lane]    + n1b[lane]);
    hbuf[n][lane+64] = __float2bfloat16((v1-mean)*rstd*n1g[lane+64] + n1b[lane+64]);
  }
  __syncthreads();

  // ---- phase 2: QKV GEMM via MFMA. wave w -> cols 96w..96w+95 ----
  {
    const int ncol0 = wave * 96;
    f32x4 acc[4][6] = {};
    for (int ks = 0; ks < 4; ++ks) {
      short8 af[4];
      #pragma unroll
      for (int mt = 0; mt < 4; ++mt)
        af[mt] = *(const short8*)(&hbuf[mt*16 + l15][ks*32 + quad*8]);
      #pragma unroll
      for (int nt = 0; nt < 6; ++nt) {
        short8 bf = *(const short8*)(qkvwb + (ncol0 + nt*16 + l15)*128 + ks*32 + quad*8);
        #pragma unroll
        for (int mt = 0; mt < 4; ++mt)
          acc[mt][nt] = __builtin_amdgcn_mfma_f32_16x16x32_bf16(af[mt], bf, acc[mt][nt], 0, 0, 0);
      }
    }
    #pragma unroll
    for (int nt = 0; nt < 6; ++nt) {
      int n = ncol0 + nt*16 + l15;
      float bias = qkvb[n];
      int which = n >> 7, nn = n & 127, hh = nn >> 5, d = nn & 31;
      #pragma unroll
      for (int mt = 0; mt < 4; ++mt) {
        #pragma unroll
        for (int r = 0; r < 4; ++r) {
          int m = mt*16 + quad*4 + r;              // C/D: col=lane&15, row=quad*4+reg
          if (m < 49) {
            float v = acc[mt][nt][r] + bias;
            if (which == 0) v *= 0.17677669529663687f;  // 1/sqrt(32)
            qkvbuf[which][hh][m][d] = __float2bfloat16(v);
          }
        }
      }
    }
  }
  __syncthreads();

  // ---- phase 3: attention. wave = head, lane = query row (49 active) ----
  if (lane < 49) {
    const int h = wave;
    float qd[32];
    const uint4* q4 = (const uint4*)(&qkvbuf[0][h][lane][0]);
    #pragma unroll
    for (int i = 0; i < 4; ++i) {
      uint4 u = q4[i];
      qd[i*8+0]=bl(u.x); qd[i*8+1]=bh(u.x); qd[i*8+2]=bl(u.y); qd[i*8+3]=bh(u.y);
      qd[i*8+4]=bl(u.z); qd[i*8+5]=bh(u.z); qd[i*8+6]=bl(u.w); qd[i*8+7]=bh(u.w);
    }
    const float* brow = biasf + h*2401 + lane*49;
    float p[49];
    float mx = -3.0e38f;
    #pragma unroll
    for (int m = 0; m < 49; ++m) {
      const uint4* k4 = (const uint4*)(&qkvbuf[1][h][m][0]);
      float s = 0.f;
      #pragma unroll
      for (int i = 0; i < 4; ++i) {
        uint4 u = k4[i];
        s += qd[i*8+0]*bl(u.x)+qd[i*8+1]*bh(u.x)+qd[i*8+2]*bl(u.y)+qd[i*8+3]*bh(u.y)
           + qd[i*8+4]*bl(u.z)+qd[i*8+5]*bh(u.z)+qd[i*8+6]*bl(u.w)+qd[i*8+7]*bh(u.w);
      }
      s += brow[m];
      p[m] = s;
      mx = fmaxf(mx, s);
    }
    float sum = 0.f;
    #pragma unroll
    for (int m = 0; m < 49; ++m) { p[m] = __expf(p[m] - mx); sum += p[m]; }
    float inv = 1.f / sum;
    float o[32];
    #pragma unroll
    for (int d = 0; d < 32; ++d) o[d] = 0.f;
    #pragma unroll
    for (int m = 0; m < 49; ++m) {
      const uint4* v4 = (const uint4*)(&qkvbuf[2][h][m][0]);
      float pm = p[m];
      #pragma unroll
      for (int i = 0; i < 4; ++i) {
        uint4 u = v4[i];
        o[i*8+0]+=pm*bl(u.x); o[i*8+1]+=pm*bh(u.x); o[i*8+2]+=pm*bl(u.y); o[i*8+3]+=pm*bh(u.y);
        o[i*8+4]+=pm*bl(u.z); o[i*8+5]+=pm*bh(u.z); o[i*8+6]+=pm*bl(u.w); o[i*8+7]+=pm*bh(u.w);
      }
    }
    #pragma unroll
    for (int d = 0; d < 32; ++d)
      hbuf[lane][h*32 + d] = __float2bfloat16(o[d] * inv);
  }
  __syncthreads();

  // ---- phase 4: proj GEMM via MFMA + shortcut, scatter (roll +3 == same token) ----
  {
    const int ncol0 = wave * 32;
    f32x4 acc[4][2] = {};
    for (int ks = 0; ks < 4; ++ks) {
      short8 af[4];
      #pragma unroll
      for (int mt = 0; mt < 4; ++mt)
        af[mt] = *(const short8*)(&hbuf[mt*16 + l15][ks*32 + quad*8]);
      #pragma unroll
      for (int nt = 0; nt < 2; ++nt) {
        short8 bf = *(const short8*)(projwb + (ncol0 + nt*16 + l15)*128 + ks*32 + quad*8);
        #pragma unroll
        for (int mt = 0; mt < 4; ++mt)
          acc[mt][nt] = __builtin_amdgcn_mfma_f32_16x16x32_bf16(af[mt], bf, acc[mt][nt], 0, 0, 0);
      }
    }
    #pragma unroll
    for (int nt = 0; nt < 2; ++nt) {
      int n = ncol0 + nt*16 + l15;
      float pb = projb[n];
      #pragma unroll
      for (int mt = 0; mt < 4; ++mt) {
        #pragma unroll
        for (int r = 0; r < 4; ++r) {
          int m = mt*16 + quad*4 + r;
          if (m < 49) {
            int rr = m / 7, cc = m - rr * 7;
            int si = wi*7 + rr + 3; if (si >= 56) si -= 56;
            int sj = wj*7 + cc + 3; if (sj >= 56) sj -= 56;
            int o = (b*3136 + si*56 + sj) * 128 + n;
            x2[o] = acc[mt][nt][r] + pb + x[o];
          }
        }
      }
    }
  }
}

// ---------------- Kernel B: LN2 + MLP(gelu) + residual, MFMA ----------------
__global__ __launch_bounds__(256) void mlp_kernel(
    const float* x2,            // aliases out (d_out) — no restrict
    const float* __restrict__ n2g, const float* __restrict__ n2b,
    const __hip_bfloat16* __restrict__ w1b, const float* __restrict__ b1,
    const __hip_bfloat16* __restrict__ w2b, const float* __restrict__ b2,
    float* out)
{
  __shared__ alignas(16) __hip_bfloat16 lnb[32][136];
  __shared__ alignas(16) __hip_bfloat16 hb[32][520];
  const int tid = threadIdx.x, wave = tid >> 6, lane = tid & 63;
  const int l15 = lane & 15, quad = lane >> 4;
  const int tok0 = blockIdx.x * 32;

  // ---- LN2 for 32 tokens ----
  for (int t = wave; t < 32; t += 4) {
    const float* xr = x2 + (tok0 + t)*128;
    float v0 = xr[lane], v1 = xr[lane + 64];
    float s = v0 + v1, sq = v0*v0 + v1*v1;
    #pragma unroll
    for (int off = 32; off > 0; off >>= 1) {
      s  += __shfl_xor(s,  off);
      sq += __shfl_xor(sq, off);
    }
    float mean = s * 0.0078125f;
    float var  = sq * 0.0078125f - mean*mean;
    float rstd = rsqrtf(var + 1e-5f);
    lnb[t][lane]    = __float2bfloat16((v0-mean)*rstd*n2g[lane]    + n2b[lane]);
    lnb[t][lane+64] = __float2bfloat16((v1-mean)*rstd*n2g[lane+64] + n2b[lane+64]);
  }
  __syncthreads();

  // ---- GEMM1 (N=512, K=128) + GELU -> hb. wave w -> cols 128w.. ----
  {
    const int ncol0 = wave * 128;
    f32x4 acc[2][8] = {};
    for (int ks = 0; ks < 4; ++ks) {
      short8 af[2];
      #pragma unroll
      for (int mt = 0; mt < 2; ++mt)
        af[mt] = *(const short8*)(&lnb[mt*16 + l15][ks*32 + quad*8]);
      #pragma unroll
      for (int nt = 0; nt < 8; ++nt) {
        short8 bf = *(const short8*)(w1b + (ncol0 + nt*16 + l15)*128 + ks*32 + quad*8);
        #pragma unroll
        for (int mt = 0; mt < 2; ++mt)
          acc[mt][nt] = __builtin_amdgcn_mfma_f32_16x16x32_bf16(af[mt], bf, acc[mt][nt], 0, 0, 0);
      }
    }
    #pragma unroll
    for (int nt = 0; nt < 8; ++nt) {
      int n = ncol0 + nt*16 + l15;
      float bb = b1[n];
      #pragma unroll
      for (int mt = 0; mt < 2; ++mt) {
        #pragma unroll
        for (int r = 0; r < 4; ++r) {
          int m = mt*16 + quad*4 + r;
          float v = acc[mt][nt][r] + bb;
          v = 0.5f * v * (1.f + erff(v * 0.70710678118654752f));
          hb[m][n] = __float2bfloat16(v);
        }
      }
    }
  }
  __syncthreads();

  // ---- GEMM2 (N=128, K=512) + bias + residual. wave w -> cols 32w.. ----
  {
    const int ncol0 = wave * 32;
    f32x4 acc[2][2] = {};
    for (int ks = 0; ks < 16; ++ks) {
      short8 af[2];
      #pragma unroll
      for (int mt = 0; mt < 2; ++mt)
        af[mt] = *(const short8*)(&hb[mt*16 + l15][ks*32 + quad*8]);
      #pragma unroll
      for (int nt = 0; nt < 2; ++nt) {
        short8 bf = *(const short8*)(w2b + (ncol0 + nt*16 + l15)*512 + ks*32 + quad*8);
        #pragma unroll
        for (int mt = 0; mt < 2; ++mt)
          acc[mt][nt] = __builtin_amdgcn_mfma_f32_16x16x32_bf16(af[mt], bf, acc[mt][nt], 0, 0, 0);
      }
    }
    #pragma unroll
    for (int nt = 0; nt < 2; ++nt) {
      int n = ncol0 + nt*16 + l15;
      float bb = b2[n];
      #pragma unroll
      for (int mt = 0; mt < 2; ++mt) {
        #pragma unroll
        for (int r = 0; r < 4; ++r) {
          int m = mt*16 + quad*4 + r;
          int o = (tok0 + m)*128 + n;
          out[o] = acc[mt][nt][r] + bb + x2[o];
        }
      }
    }
  }
}

extern "C" void kernel_launch(void* const* d_in, const int* in_sizes, int n_in,
                              void* d_out, int out_size, void* d_ws, size_t ws_size,
                              hipStream_t stream) {
  const float* x     = (const float*)d_in[0];
  const float* n1g   = (const float*)d_in[3];
  const float* n1b   = (const float*)d_in[4];
  const float* qkvw  = (const float*)d_in[5];
  const float* qkvb  = (const float*)d_in[6];
  const float* tab   = (const float*)d_in[7];
  const int*   ridx  = (const int*)d_in[8];
  const float* projw = (const float*)d_in[9];
  const float* projb = (const float*)d_in[10];
  const float* n2g   = (const float*)d_in[11];
  const float* n2b   = (const float*)d_in[12];
  const float* w1    = (const float*)d_in[13];
  const float* b1    = (const float*)d_in[14];
  const float* w2    = (const float*)d_in[15];
  const float* b2    = (const float*)d_in[16];
  float* outp = (float*)d_out;

  __hip_bfloat16* wsb = (__hip_bfloat16*)d_ws;
  float* biasf = (float*)((char*)d_ws + BIAS_BYTE_OFF);
  const __hip_bfloat16* qkvwb = wsb + QKVW_OFF;
  const __hip_bfloat16* projwb = wsb + PROJW_OFF;
  const __hip_bfloat16* w1b = wsb + W1_OFF;
  const __hip_bfloat16* w2b = wsb + W2_OFF;

  hipLaunchKernelGGL(conv_kernel, dim3(806), dim3(256), 0, stream,
                     qkvw, projw, w1, w2, tab, ridx, wsb, biasf);
  hipLaunchKernelGGL(attn_kernel, dim3(NWIN), dim3(256), 0, stream,
                     x, n1g, n1b, qkvwb, qkvb, biasf, projwb, projb, outp);
  hipLaunchKernelGGL(mlp_kernel, dim3(TOK/32), dim3(256), 0, stream,
                     outp, n2g, n2b, w1b, b1, w2b, b2, outp);
}

// Round 4
// 348.951 us; speedup vs baseline: 9.1785x; 1.8401x over previous
//
#include <hip/hip_runtime.h>
#include <hip/hip_bf16.h>

// Swin block, B=32 H=W=56 C=128, ws=7 (N=49), nh=4 (hd=32), shift=3, hid=512.
// fp32 in/out. All GEMMs AND attention (QK^T, AV) via mfma_f32_16x16x32_bf16.
// roll(-3) gather == roll(+3) scatter target -> fully fused windows.
// d_ws: bf16 weights + padded bias^T [4][64][64] fp32. x2 lives in d_out.

#define TOK  100352
#define NWIN 2048

typedef short short8  __attribute__((ext_vector_type(8)));
typedef short short4v __attribute__((ext_vector_type(4)));
typedef float f32x4   __attribute__((ext_vector_type(4)));

#define QKVW_OFF  0        // 384*128 bf16
#define PROJW_OFF 49152    // 128*128
#define W1_OFF    65536    // 512*128
#define W2_OFF    131072   // 128*512
#define BIAS_BYTE_OFF 393216  // biasT[4][64][64] fp32 (padded, 0 outside 49x49)

__device__ __forceinline__ short f2bs(float v) {
  __hip_bfloat16 h = __float2bfloat16(v);
  union { __hip_bfloat16 h; short s; } u; u.h = h; return u.s;
}
__device__ __forceinline__ float gelu_f(float v) {
  float u = v * (0.7978845608028654f + 0.03567740814f * v * v);
  return v * __builtin_amdgcn_rcpf(1.f + __expf(-2.f * u));
}

// ---------------- pre-pass: weights -> bf16, padded bias^T gather ----------------
__global__ __launch_bounds__(256) void conv_kernel(
    const float* __restrict__ qkvw, const float* __restrict__ projw,
    const float* __restrict__ w1,   const float* __restrict__ w2,
    const float* __restrict__ tab,  const int* __restrict__ ridx,
    __hip_bfloat16* __restrict__ wsb, float* __restrict__ biasT)
{
  int idx = blockIdx.x * 256 + threadIdx.x;
  if (idx < 49152)       wsb[QKVW_OFF + idx]          = __float2bfloat16(qkvw[idx]);
  else if (idx < 65536)  wsb[PROJW_OFF + idx - 49152] = __float2bfloat16(projw[idx - 49152]);
  else if (idx < 131072) wsb[W1_OFF + idx - 65536]    = __float2bfloat16(w1[idx - 65536]);
  else if (idx < 196608) wsb[W2_OFF + idx - 131072]   = __float2bfloat16(w2[idx - 131072]);
  else if (idx < 212992) {
    int i = idx - 196608;
    int h = i >> 12, m = (i >> 6) & 63, n = i & 63;   // biasT[h][m=key][n=query]
    biasT[i] = (m < 49 && n < 49) ? tab[ridx[n*49 + m]*4 + h] : 0.f;
  }
}

// ---------------- Kernel A: LN1 + window attention + proj + shortcut ----------------
__global__ __launch_bounds__(256) void attn_kernel(
    const float* __restrict__ x,
    const float* __restrict__ n1g, const float* __restrict__ n1b,
    const __hip_bfloat16* __restrict__ qkvwb, const float* __restrict__ qkvb,
    const float* __restrict__ biasT,
    const __hip_bfloat16* __restrict__ projwb, const float* __restrict__ projb,
    float* __restrict__ x2)
{
  __shared__ alignas(16) __hip_bfloat16 hbuf[64][136];      // h tile / o tile
  __shared__ alignas(16) __hip_bfloat16 qk[4][2][64][40];   // [head][q|k][token][d]; P overlays
  __shared__ alignas(16) __hip_bfloat16 vT[4][32][72];      // [head][d][m] (m 49..63 zeroed)
  const int tid = threadIdx.x, wave = tid >> 6, lane = tid & 63;
  const int l15 = lane & 15, quad = lane >> 4;
  const int b = blockIdx.x >> 6, wi = (blockIdx.x >> 3) & 7, wj = blockIdx.x & 7;

  // ---- phase 1: LN1 over source rows (roll -3) -> hbuf bf16 ----
  {
    float g0 = n1g[lane], g1 = n1g[lane+64], e0 = n1b[lane], e1 = n1b[lane+64];
    for (int n = wave; n < 49; n += 4) {
      int r = n / 7, c = n - r * 7;
      int si = wi*7 + r + 3; if (si >= 56) si -= 56;
      int sj = wj*7 + c + 3; if (sj >= 56) sj -= 56;
      const float* xr = x + (b*3136 + si*56 + sj) * 128;
      float v0 = xr[lane], v1 = xr[lane + 64];
      float s = v0 + v1, sq = v0*v0 + v1*v1;
      #pragma unroll
      for (int off = 32; off > 0; off >>= 1) {
        s  += __shfl_xor(s,  off);
        sq += __shfl_xor(sq, off);
      }
      float mean = s * 0.0078125f;
      float var  = sq * 0.0078125f - mean*mean;
      float rstd = rsqrtf(var + 1e-5f);
      hbuf[n][lane]    = __float2bfloat16((v0-mean)*rstd*g0 + e0);
      hbuf[n][lane+64] = __float2bfloat16((v1-mean)*rstd*g1 + e1);
    }
  }
  __syncthreads();

  // ---- phase 2: QKV GEMM. Q/K swapped (D[f][m]) for vector LDS writes;
  //      V original (D[m][f]) -> writes V^T directly. 96 MFMA/wave. ----
  {
    const int which = wave >> 1;          // 0=Q (waves 0,1), 1=K (waves 2,3)
    const int fb    = (wave & 1) * 64;    // feature base within Q or K
    const int vb    = wave * 32;          // V feature range [vb, vb+32)
    f32x4 asw[4][4] = {};                 // [ft][mt]  D[f][m]
    f32x4 aor[4][2] = {};                 // [mt][nt]  D[m][f]  (V)
    #pragma unroll
    for (int ks = 0; ks < 4; ++ks) {
      short8 hf[4];
      #pragma unroll
      for (int mt = 0; mt < 4; ++mt)
        hf[mt] = *(const short8*)(&hbuf[mt*16 + l15][ks*32 + quad*8]);
      #pragma unroll
      for (int ft = 0; ft < 4; ++ft) {
        short8 wf = *(const short8*)(qkvwb + (which*128 + fb + ft*16 + l15)*128 + ks*32 + quad*8);
        #pragma unroll
        for (int mt = 0; mt < 4; ++mt)
          asw[ft][mt] = __builtin_amdgcn_mfma_f32_16x16x32_bf16(wf, hf[mt], asw[ft][mt], 0, 0, 0);
      }
      #pragma unroll
      for (int nt = 0; nt < 2; ++nt) {
        short8 wf = *(const short8*)(qkvwb + (256 + vb + nt*16 + l15)*128 + ks*32 + quad*8);
        #pragma unroll
        for (int mt = 0; mt < 4; ++mt)
          aor[mt][nt] = __builtin_amdgcn_mfma_f32_16x16x32_bf16(hf[mt], wf, aor[mt][nt], 0, 0, 0);
      }
    }
    // Q/K epilogue: f = which*128 + fb + ft*16 + quad*4 + r ; m = mt*16 + l15
    const float qs = (which == 0) ? 0.17677669529663687f : 1.0f;
    #pragma unroll
    for (int ft = 0; ft < 4; ++ft) {
      int fo = fb + ft*16 + quad*4;              // within-which feature offset
      int hh = fo >> 5, d0 = fo & 31;
      float bb[4];
      #pragma unroll
      for (int r = 0; r < 4; ++r) bb[r] = qkvb[which*128 + fo + r];
      #pragma unroll
      for (int mt = 0; mt < 4; ++mt) {
        int m = mt*16 + l15;
        if (m < 49) {
          short4v pk;
          #pragma unroll
          for (int r = 0; r < 4; ++r) pk[r] = f2bs((asw[ft][mt][r] + bb[r]) * qs);
          *(short4v*)(&qk[hh][which][m][d0]) = pk;
        }
      }
    }
    // V epilogue -> vT[hh][d][m], zero-pad m in [49,64)
    #pragma unroll
    for (int nt = 0; nt < 2; ++nt) {
      int n = vb + nt*16 + l15;                   // V feature 0..127
      int hh = n >> 5, d = n & 31;
      float bia = qkvb[256 + n];
      #pragma unroll
      for (int mt = 0; mt < 4; ++mt) {
        int m0 = mt*16 + quad*4;
        short4v pk;
        #pragma unroll
        for (int r = 0; r < 4; ++r) {
          float v = (m0 + r < 49) ? (aor[mt][nt][r] + bia) : 0.f;
          pk[r] = f2bs(v);
        }
        *(short4v*)(&vT[hh][d][m0]) = pk;
      }
    }
  }
  __syncthreads();

  // ---- phase 3: attention, wave = head. S^T = K·Q^T (MFMA), softmax over m,
  //      P -> LDS (overlays Q/K), O = V^T·P^T (MFMA) -> hbuf o-tile. ----
  {
    const int h = wave;
    __hip_bfloat16* qbase = &qk[h][0][0][0];
    __hip_bfloat16* kbase = &qk[h][1][0][0];
    short8 kf[4], qf[4];
    #pragma unroll
    for (int mt = 0; mt < 4; ++mt) kf[mt] = *(const short8*)(kbase + (mt*16 + l15)*40 + quad*8);
    #pragma unroll
    for (int nt = 0; nt < 4; ++nt) qf[nt] = *(const short8*)(qbase + (nt*16 + l15)*40 + quad*8);
    f32x4 sacc[4][4] = {};   // [mt][nt] : m = mt*16+quad*4+r, n = nt*16+l15
    #pragma unroll
    for (int mt = 0; mt < 4; ++mt)
      #pragma unroll
      for (int nt = 0; nt < 4; ++nt)
        sacc[mt][nt] = __builtin_amdgcn_mfma_f32_16x16x32_bf16(kf[mt], qf[nt], sacc[mt][nt], 0, 0, 0);

    const float* bT = biasT + h*4096;
    #pragma unroll
    for (int mt = 0; mt < 4; ++mt)
      #pragma unroll
      for (int nt = 0; nt < 4; ++nt)
        #pragma unroll
        for (int r = 0; r < 4; ++r)
          sacc[mt][nt][r] += bT[(mt*16 + quad*4 + r)*64 + nt*16 + l15];

    __hip_bfloat16* pb = qbase;   // P[n][m], stride 72, overlays Q+K region (5120 el)
    #pragma unroll
    for (int nt = 0; nt < 4; ++nt) {
      float mx = -1e30f;
      #pragma unroll
      for (int mt = 0; mt < 3; ++mt)
        #pragma unroll
        for (int r = 0; r < 4; ++r) mx = fmaxf(mx, sacc[mt][nt][r]);
      mx = fmaxf(mx, (quad == 0) ? sacc[3][nt][0] : -1e30f);   // m=48 only
      mx = fmaxf(mx, __shfl_xor(mx, 16));
      mx = fmaxf(mx, __shfl_xor(mx, 32));
      float sum = 0.f;
      #pragma unroll
      for (int mt = 0; mt < 3; ++mt)
        #pragma unroll
        for (int r = 0; r < 4; ++r) {
          float e = __expf(sacc[mt][nt][r] - mx);
          sacc[mt][nt][r] = e; sum += e;
        }
      {
        float e = (quad == 0) ? __expf(sacc[3][nt][0] - mx) : 0.f;
        sacc[3][nt][0] = e; sacc[3][nt][1] = 0.f; sacc[3][nt][2] = 0.f; sacc[3][nt][3] = 0.f;
        sum += e;
      }
      sum += __shfl_xor(sum, 16);
      sum += __shfl_xor(sum, 32);
      float inv = 1.f / sum;
      int n = nt*16 + l15;
      #pragma unroll
      for (int mt = 0; mt < 4; ++mt) {
        short4v pk;
        #pragma unroll
        for (int r = 0; r < 4; ++r) pk[r] = f2bs(sacc[mt][nt][r] * inv);
        *(short4v*)(pb + n*72 + mt*16 + quad*4) = pk;
      }
    }

    // AV: A=V^T rows d, B=P rows n -> D[d][n]
    f32x4 oacc[2][4] = {};
    #pragma unroll
    for (int kt = 0; kt < 2; ++kt) {
      short8 vf[2], pf[4];
      #pragma unroll
      for (int dt = 0; dt < 2; ++dt)
        vf[dt] = *(const short8*)(&vT[h][dt*16 + l15][kt*32 + quad*8]);
      #pragma unroll
      for (int nc = 0; nc < 4; ++nc)
        pf[nc] = *(const short8*)(pb + (nc*16 + l15)*72 + kt*32 + quad*8);
      #pragma unroll
      for (int dt = 0; dt < 2; ++dt)
        #pragma unroll
        for (int nc = 0; nc < 4; ++nc)
          oacc[dt][nc] = __builtin_amdgcn_mfma_f32_16x16x32_bf16(vf[dt], pf[nc], oacc[dt][nc], 0, 0, 0);
    }
    // O[n][d] -> hbuf[n][h*32+d]; d = dt*16+quad*4+r (consecutive r), n = nc*16+l15
    #pragma unroll
    for (int dt = 0; dt < 2; ++dt)
      #pragma unroll
      for (int nc = 0; nc < 4; ++nc) {
        int n = nc*16 + l15;
        if (n < 49) {
          short4v pk;
          #pragma unroll
          for (int r = 0; r < 4; ++r) pk[r] = f2bs(oacc[dt][nc][r]);
          *(short4v*)(&hbuf[n][h*32 + dt*16 + quad*4]) = pk;
        }
      }
  }
  __syncthreads();

  // ---- phase 4: proj + shortcut, scatter (roll +3 == same token) ----
  {
    const int ncol0 = wave * 32;
    f32x4 acc[4][2] = {};
    #pragma unroll
    for (int ks = 0; ks < 4; ++ks) {
      short8 af[4];
      #pragma unroll
      for (int mt = 0; mt < 4; ++mt)
        af[mt] = *(const short8*)(&hbuf[mt*16 + l15][ks*32 + quad*8]);
      #pragma unroll
      for (int nt = 0; nt < 2; ++nt) {
        short8 bf = *(const short8*)(projwb + (ncol0 + nt*16 + l15)*128 + ks*32 + quad*8);
        #pragma unroll
        for (int mt = 0; mt < 4; ++mt)
          acc[mt][nt] = __builtin_amdgcn_mfma_f32_16x16x32_bf16(af[mt], bf, acc[mt][nt], 0, 0, 0);
      }
    }
    #pragma unroll
    for (int nt = 0; nt < 2; ++nt) {
      int n = ncol0 + nt*16 + l15;
      float pbv = projb[n];
      #pragma unroll
      for (int mt = 0; mt < 4; ++mt) {
        #pragma unroll
        for (int r = 0; r < 4; ++r) {
          int m = mt*16 + quad*4 + r;
          if (m < 49) {
            int rr = m / 7, cc = m - rr * 7;
            int si = wi*7 + rr + 3; if (si >= 56) si -= 56;
            int sj = wj*7 + cc + 3; if (sj >= 56) sj -= 56;
            int o = (b*3136 + si*56 + sj) * 128 + n;
            x2[o] = acc[mt][nt][r] + pbv + x[o];
          }
        }
      }
    }
  }
}

// ---------------- Kernel B: LN2 + MLP(fast gelu) + residual ----------------
__global__ __launch_bounds__(256) void mlp_kernel(
    const float* x2,            // aliases out
    const float* __restrict__ n2g, const float* __restrict__ n2b,
    const __hip_bfloat16* __restrict__ w1b, const float* __restrict__ b1,
    const __hip_bfloat16* __restrict__ w2b, const float* __restrict__ b2,
    float* out)
{
  __shared__ alignas(16) __hip_bfloat16 lnb[32][136];
  __shared__ alignas(16) __hip_bfloat16 hb[32][520];
  const int tid = threadIdx.x, wave = tid >> 6, lane = tid & 63;
  const int l15 = lane & 15, quad = lane >> 4;
  const int tok0 = blockIdx.x * 32;

  {
    float g0 = n2g[lane], g1 = n2g[lane+64], e0 = n2b[lane], e1 = n2b[lane+64];
    for (int t = wave; t < 32; t += 4) {
      const float* xr = x2 + (tok0 + t)*128;
      float v0 = xr[lane], v1 = xr[lane + 64];
      float s = v0 + v1, sq = v0*v0 + v1*v1;
      #pragma unroll
      for (int off = 32; off > 0; off >>= 1) {
        s  += __shfl_xor(s,  off);
        sq += __shfl_xor(sq, off);
      }
      float mean = s * 0.0078125f;
      float var  = sq * 0.0078125f - mean*mean;
      float rstd = rsqrtf(var + 1e-5f);
      lnb[t][lane]    = __float2bfloat16((v0-mean)*rstd*g0 + e0);
      lnb[t][lane+64] = __float2bfloat16((v1-mean)*rstd*g1 + e1);
    }
  }
  __syncthreads();

  // GEMM1 swapped: D[j][m]; wave covers j in [wave*128, +128)
  {
    const int jb = wave * 128;
    f32x4 acc1[8][2] = {};
    #pragma unroll
    for (int ks = 0; ks < 4; ++ks) {
      short8 lf[2];
      #pragma unroll
      for (int mt = 0; mt < 2; ++mt)
        lf[mt] = *(const short8*)(&lnb[mt*16 + l15][ks*32 + quad*8]);
      #pragma unroll
      for (int jt = 0; jt < 8; ++jt) {
        short8 wf = *(const short8*)(w1b + (jb + jt*16 + l15)*128 + ks*32 + quad*8);
        #pragma unroll
        for (int mt = 0; mt < 2; ++mt)
          acc1[jt][mt] = __builtin_amdgcn_mfma_f32_16x16x32_bf16(wf, lf[mt], acc1[jt][mt], 0, 0, 0);
      }
    }
    #pragma unroll
    for (int jt = 0; jt < 8; ++jt) {
      int j0 = jb + jt*16 + quad*4;
      float bb[4];
      #pragma unroll
      for (int r = 0; r < 4; ++r) bb[r] = b1[j0 + r];
      #pragma unroll
      for (int mt = 0; mt < 2; ++mt) {
        int m = mt*16 + l15;
        short4v pk;
        #pragma unroll
        for (int r = 0; r < 4; ++r) pk[r] = f2bs(gelu_f(acc1[jt][mt][r] + bb[r]));
        *(short4v*)(&hb[m][j0]) = pk;
      }
    }
  }
  __syncthreads();

  // GEMM2 original: D[m][f]; wave covers f in [wave*32, +32)
  {
    const int fb2 = wave * 32;
    f32x4 acc2[2][2] = {};
    #pragma unroll
    for (int ks = 0; ks < 16; ++ks) {
      short8 af[2];
      #pragma unroll
      for (int mt = 0; mt < 2; ++mt)
        af[mt] = *(const short8*)(&hb[mt*16 + l15][ks*32 + quad*8]);
      #pragma unroll
      for (int nt = 0; nt < 2; ++nt) {
        short8 bf = *(const short8*)(w2b + (fb2 + nt*16 + l15)*512 + ks*32 + quad*8);
        #pragma unroll
        for (int mt = 0; mt < 2; ++mt)
          acc2[mt][nt] = __builtin_amdgcn_mfma_f32_16x16x32_bf16(af[mt], bf, acc2[mt][nt], 0, 0, 0);
      }
    }
    #pragma unroll
    for (int nt = 0; nt < 2; ++nt) {
      int f = fb2 + nt*16 + l15;
      float bb = b2[f];
      #pragma unroll
      for (int mt = 0; mt < 2; ++mt) {
        #pragma unroll
        for (int r = 0; r < 4; ++r) {
          int m = mt*16 + quad*4 + r;
          int o = (tok0 + m)*128 + f;
          out[o] = acc2[mt][nt][r] + bb + x2[o];
        }
      }
    }
  }
}

extern "C" void kernel_launch(void* const* d_in, const int* in_sizes, int n_in,
                              void* d_out, int out_size, void* d_ws, size_t ws_size,
                              hipStream_t stream) {
  const float* x     = (const float*)d_in[0];
  const float* n1g   = (const float*)d_in[3];
  const float* n1b   = (const float*)d_in[4];
  const float* qkvw  = (const float*)d_in[5];
  const float* qkvb  = (const float*)d_in[6];
  const float* tab   = (const float*)d_in[7];
  const int*   ridx  = (const int*)d_in[8];
  const float* projw = (const float*)d_in[9];
  const float* projb = (const float*)d_in[10];
  const float* n2g   = (const float*)d_in[11];
  const float* n2b   = (const float*)d_in[12];
  const float* w1    = (const float*)d_in[13];
  const float* b1    = (const float*)d_in[14];
  const float* w2    = (const float*)d_in[15];
  const float* b2    = (const float*)d_in[16];
  float* outp = (float*)d_out;

  __hip_bfloat16* wsb = (__hip_bfloat16*)d_ws;
  float* biasT = (float*)((char*)d_ws + BIAS_BYTE_OFF);

  hipLaunchKernelGGL(conv_kernel, dim3(832), dim3(256), 0, stream,
                     qkvw, projw, w1, w2, tab, ridx, wsb, biasT);
  hipLaunchKernelGGL(attn_kernel, dim3(NWIN), dim3(256), 0, stream,
                     x, n1g, n1b, wsb + QKVW_OFF, qkvb, biasT, wsb + PROJW_OFF, projb, outp);
  hipLaunchKernelGGL(mlp_kernel, dim3(TOK/32), dim3(256), 0, stream,
                     outp, n2g, n2b, wsb + W1_OFF, b1, wsb + W2_OFF, b2, outp);
}

// Round 5
// 322.830 us; speedup vs baseline: 9.9211x; 1.0809x over previous
//
#include <hip/hip_runtime.h>
#include <hip/hip_bf16.h>

// Swin block, B=32 H=W=56 C=128, ws=7 (N=49), nh=4 (hd=32), shift=3, hid=512.
// fp32 in/out. All GEMMs AND attention (QK^T, AV) via mfma_f32_16x16x32_bf16.
// roll(-3) gather == roll(+3) scatter target -> fully fused windows.
// d_ws: bf16 weights + padded bias^T [4][64][64] fp32. x2 lives in d_out.
// R5: mlp hidden dim processed in 2 chunks of 256 -> LDS 41984->25600 B
//     (3->6 blocks/CU) to attack the latency stall (all pipes <20% busy).

#define TOK  100352
#define NWIN 2048

typedef short short8  __attribute__((ext_vector_type(8)));
typedef short short4v __attribute__((ext_vector_type(4)));
typedef float f32x4   __attribute__((ext_vector_type(4)));

#define QKVW_OFF  0        // 384*128 bf16
#define PROJW_OFF 49152    // 128*128
#define W1_OFF    65536    // 512*128
#define W2_OFF    131072   // 128*512
#define BIAS_BYTE_OFF 393216  // biasT[4][64][64] fp32 (padded, 0 outside 49x49)

__device__ __forceinline__ short f2bs(float v) {
  __hip_bfloat16 h = __float2bfloat16(v);
  union { __hip_bfloat16 h; short s; } u; u.h = h; return u.s;
}
__device__ __forceinline__ float gelu_f(float v) {
  float u = v * (0.7978845608028654f + 0.03567740814f * v * v);
  return v * __builtin_amdgcn_rcpf(1.f + __expf(-2.f * u));
}

// ---------------- pre-pass: weights -> bf16, padded bias^T gather ----------------
__global__ __launch_bounds__(256) void conv_kernel(
    const float* __restrict__ qkvw, const float* __restrict__ projw,
    const float* __restrict__ w1,   const float* __restrict__ w2,
    const float* __restrict__ tab,  const int* __restrict__ ridx,
    __hip_bfloat16* __restrict__ wsb, float* __restrict__ biasT)
{
  int idx = blockIdx.x * 256 + threadIdx.x;
  if (idx < 49152)       wsb[QKVW_OFF + idx]          = __float2bfloat16(qkvw[idx]);
  else if (idx < 65536)  wsb[PROJW_OFF + idx - 49152] = __float2bfloat16(projw[idx - 49152]);
  else if (idx < 131072) wsb[W1_OFF + idx - 65536]    = __float2bfloat16(w1[idx - 65536]);
  else if (idx < 196608) wsb[W2_OFF + idx - 131072]   = __float2bfloat16(w2[idx - 131072]);
  else if (idx < 212992) {
    int i = idx - 196608;
    int h = i >> 12, m = (i >> 6) & 63, n = i & 63;   // biasT[h][m=key][n=query]
    biasT[i] = (m < 49 && n < 49) ? tab[ridx[n*49 + m]*4 + h] : 0.f;
  }
}

// ---------------- Kernel A: LN1 + window attention + proj + shortcut ----------------
__global__ __launch_bounds__(256) void attn_kernel(
    const float* __restrict__ x,
    const float* __restrict__ n1g, const float* __restrict__ n1b,
    const __hip_bfloat16* __restrict__ qkvwb, const float* __restrict__ qkvb,
    const float* __restrict__ biasT,
    const __hip_bfloat16* __restrict__ projwb, const float* __restrict__ projb,
    float* __restrict__ x2)
{
  __shared__ alignas(16) __hip_bfloat16 hbuf[64][136];      // h tile / o tile
  __shared__ alignas(16) __hip_bfloat16 qk[4][2][64][40];   // [head][q|k][token][d]; P overlays
  __shared__ alignas(16) __hip_bfloat16 vT[4][32][72];      // [head][d][m] (m 49..63 zeroed)
  const int tid = threadIdx.x, wave = tid >> 6, lane = tid & 63;
  const int l15 = lane & 15, quad = lane >> 4;
  const int b = blockIdx.x >> 6, wi = (blockIdx.x >> 3) & 7, wj = blockIdx.x & 7;

  // ---- phase 1: LN1 over source rows (roll -3) -> hbuf bf16 ----
  {
    float g0 = n1g[lane], g1 = n1g[lane+64], e0 = n1b[lane], e1 = n1b[lane+64];
    for (int n = wave; n < 49; n += 4) {
      int r = n / 7, c = n - r * 7;
      int si = wi*7 + r + 3; if (si >= 56) si -= 56;
      int sj = wj*7 + c + 3; if (sj >= 56) sj -= 56;
      const float* xr = x + (b*3136 + si*56 + sj) * 128;
      float v0 = xr[lane], v1 = xr[lane + 64];
      float s = v0 + v1, sq = v0*v0 + v1*v1;
      #pragma unroll
      for (int off = 32; off > 0; off >>= 1) {
        s  += __shfl_xor(s,  off);
        sq += __shfl_xor(sq, off);
      }
      float mean = s * 0.0078125f;
      float var  = sq * 0.0078125f - mean*mean;
      float rstd = rsqrtf(var + 1e-5f);
      hbuf[n][lane]    = __float2bfloat16((v0-mean)*rstd*g0 + e0);
      hbuf[n][lane+64] = __float2bfloat16((v1-mean)*rstd*g1 + e1);
    }
  }
  __syncthreads();

  // ---- phase 2: QKV GEMM. Q/K swapped (D[f][m]) for vector LDS writes;
  //      V original (D[m][f]) -> writes V^T directly. 96 MFMA/wave. ----
  {
    const int which = wave >> 1;          // 0=Q (waves 0,1), 1=K (waves 2,3)
    const int fb    = (wave & 1) * 64;    // feature base within Q or K
    const int vb    = wave * 32;          // V feature range [vb, vb+32)
    f32x4 asw[4][4] = {};                 // [ft][mt]  D[f][m]
    f32x4 aor[4][2] = {};                 // [mt][nt]  D[m][f]  (V)
    #pragma unroll
    for (int ks = 0; ks < 4; ++ks) {
      short8 hf[4];
      #pragma unroll
      for (int mt = 0; mt < 4; ++mt)
        hf[mt] = *(const short8*)(&hbuf[mt*16 + l15][ks*32 + quad*8]);
      #pragma unroll
      for (int ft = 0; ft < 4; ++ft) {
        short8 wf = *(const short8*)(qkvwb + (which*128 + fb + ft*16 + l15)*128 + ks*32 + quad*8);
        #pragma unroll
        for (int mt = 0; mt < 4; ++mt)
          asw[ft][mt] = __builtin_amdgcn_mfma_f32_16x16x32_bf16(wf, hf[mt], asw[ft][mt], 0, 0, 0);
      }
      #pragma unroll
      for (int nt = 0; nt < 2; ++nt) {
        short8 wf = *(const short8*)(qkvwb + (256 + vb + nt*16 + l15)*128 + ks*32 + quad*8);
        #pragma unroll
        for (int mt = 0; mt < 4; ++mt)
          aor[mt][nt] = __builtin_amdgcn_mfma_f32_16x16x32_bf16(hf[mt], wf, aor[mt][nt], 0, 0, 0);
      }
    }
    // Q/K epilogue: f = which*128 + fb + ft*16 + quad*4 + r ; m = mt*16 + l15
    const float qs = (which == 0) ? 0.17677669529663687f : 1.0f;
    #pragma unroll
    for (int ft = 0; ft < 4; ++ft) {
      int fo = fb + ft*16 + quad*4;              // within-which feature offset
      int hh = fo >> 5, d0 = fo & 31;
      float bb[4];
      #pragma unroll
      for (int r = 0; r < 4; ++r) bb[r] = qkvb[which*128 + fo + r];
      #pragma unroll
      for (int mt = 0; mt < 4; ++mt) {
        int m = mt*16 + l15;
        if (m < 49) {
          short4v pk;
          #pragma unroll
          for (int r = 0; r < 4; ++r) pk[r] = f2bs((asw[ft][mt][r] + bb[r]) * qs);
          *(short4v*)(&qk[hh][which][m][d0]) = pk;
        }
      }
    }
    // V epilogue -> vT[hh][d][m], zero-pad m in [49,64)
    #pragma unroll
    for (int nt = 0; nt < 2; ++nt) {
      int n = vb + nt*16 + l15;                   // V feature 0..127
      int hh = n >> 5, d = n & 31;
      float bia = qkvb[256 + n];
      #pragma unroll
      for (int mt = 0; mt < 4; ++mt) {
        int m0 = mt*16 + quad*4;
        short4v pk;
        #pragma unroll
        for (int r = 0; r < 4; ++r) {
          float v = (m0 + r < 49) ? (aor[mt][nt][r] + bia) : 0.f;
          pk[r] = f2bs(v);
        }
        *(short4v*)(&vT[hh][d][m0]) = pk;
      }
    }
  }
  __syncthreads();

  // ---- phase 3: attention, wave = head. S^T = K·Q^T (MFMA), softmax over m,
  //      P -> LDS (overlays Q/K), O = V^T·P^T (MFMA) -> hbuf o-tile. ----
  {
    const int h = wave;
    __hip_bfloat16* qbase = &qk[h][0][0][0];
    __hip_bfloat16* kbase = &qk[h][1][0][0];
    short8 kf[4], qf[4];
    #pragma unroll
    for (int mt = 0; mt < 4; ++mt) kf[mt] = *(const short8*)(kbase + (mt*16 + l15)*40 + quad*8);
    #pragma unroll
    for (int nt = 0; nt < 4; ++nt) qf[nt] = *(const short8*)(qbase + (nt*16 + l15)*40 + quad*8);
    f32x4 sacc[4][4] = {};   // [mt][nt] : m = mt*16+quad*4+r, n = nt*16+l15
    #pragma unroll
    for (int mt = 0; mt < 4; ++mt)
      #pragma unroll
      for (int nt = 0; nt < 4; ++nt)
        sacc[mt][nt] = __builtin_amdgcn_mfma_f32_16x16x32_bf16(kf[mt], qf[nt], sacc[mt][nt], 0, 0, 0);

    const float* bT = biasT + h*4096;
    #pragma unroll
    for (int mt = 0; mt < 4; ++mt)
      #pragma unroll
      for (int nt = 0; nt < 4; ++nt)
        #pragma unroll
        for (int r = 0; r < 4; ++r)
          sacc[mt][nt][r] += bT[(mt*16 + quad*4 + r)*64 + nt*16 + l15];

    __hip_bfloat16* pb = qbase;   // P[n][m], stride 72, overlays Q+K region (5120 el)
    #pragma unroll
    for (int nt = 0; nt < 4; ++nt) {
      float mx = -1e30f;
      #pragma unroll
      for (int mt = 0; mt < 3; ++mt)
        #pragma unroll
        for (int r = 0; r < 4; ++r) mx = fmaxf(mx, sacc[mt][nt][r]);
      mx = fmaxf(mx, (quad == 0) ? sacc[3][nt][0] : -1e30f);   // m=48 only
      mx = fmaxf(mx, __shfl_xor(mx, 16));
      mx = fmaxf(mx, __shfl_xor(mx, 32));
      float sum = 0.f;
      #pragma unroll
      for (int mt = 0; mt < 3; ++mt)
        #pragma unroll
        for (int r = 0; r < 4; ++r) {
          float e = __expf(sacc[mt][nt][r] - mx);
          sacc[mt][nt][r] = e; sum += e;
        }
      {
        float e = (quad == 0) ? __expf(sacc[3][nt][0] - mx) : 0.f;
        sacc[3][nt][0] = e; sacc[3][nt][1] = 0.f; sacc[3][nt][2] = 0.f; sacc[3][nt][3] = 0.f;
        sum += e;
      }
      sum += __shfl_xor(sum, 16);
      sum += __shfl_xor(sum, 32);
      float inv = 1.f / sum;
      int n = nt*16 + l15;
      #pragma unroll
      for (int mt = 0; mt < 4; ++mt) {
        short4v pk;
        #pragma unroll
        for (int r = 0; r < 4; ++r) pk[r] = f2bs(sacc[mt][nt][r] * inv);
        *(short4v*)(pb + n*72 + mt*16 + quad*4) = pk;
      }
    }

    // AV: A=V^T rows d, B=P rows n -> D[d][n]
    f32x4 oacc[2][4] = {};
    #pragma unroll
    for (int kt = 0; kt < 2; ++kt) {
      short8 vf[2], pf[4];
      #pragma unroll
      for (int dt = 0; dt < 2; ++dt)
        vf[dt] = *(const short8*)(&vT[h][dt*16 + l15][kt*32 + quad*8]);
      #pragma unroll
      for (int nc = 0; nc < 4; ++nc)
        pf[nc] = *(const short8*)(pb + (nc*16 + l15)*72 + kt*32 + quad*8);
      #pragma unroll
      for (int dt = 0; dt < 2; ++dt)
        #pragma unroll
        for (int nc = 0; nc < 4; ++nc)
          oacc[dt][nc] = __builtin_amdgcn_mfma_f32_16x16x32_bf16(vf[dt], pf[nc], oacc[dt][nc], 0, 0, 0);
    }
    // O[n][d] -> hbuf[n][h*32+d]; d = dt*16+quad*4+r (consecutive r), n = nc*16+l15
    #pragma unroll
    for (int dt = 0; dt < 2; ++dt)
      #pragma unroll
      for (int nc = 0; nc < 4; ++nc) {
        int n = nc*16 + l15;
        if (n < 49) {
          short4v pk;
          #pragma unroll
          for (int r = 0; r < 4; ++r) pk[r] = f2bs(oacc[dt][nc][r]);
          *(short4v*)(&hbuf[n][h*32 + dt*16 + quad*4]) = pk;
        }
      }
  }
  __syncthreads();

  // ---- phase 4: proj + shortcut, scatter (roll +3 == same token) ----
  {
    const int ncol0 = wave * 32;
    f32x4 acc[4][2] = {};
    #pragma unroll
    for (int ks = 0; ks < 4; ++ks) {
      short8 af[4];
      #pragma unroll
      for (int mt = 0; mt < 4; ++mt)
        af[mt] = *(const short8*)(&hbuf[mt*16 + l15][ks*32 + quad*8]);
      #pragma unroll
      for (int nt = 0; nt < 2; ++nt) {
        short8 bf = *(const short8*)(projwb + (ncol0 + nt*16 + l15)*128 + ks*32 + quad*8);
        #pragma unroll
        for (int mt = 0; mt < 4; ++mt)
          acc[mt][nt] = __builtin_amdgcn_mfma_f32_16x16x32_bf16(af[mt], bf, acc[mt][nt], 0, 0, 0);
      }
    }
    #pragma unroll
    for (int nt = 0; nt < 2; ++nt) {
      int n = ncol0 + nt*16 + l15;
      float pbv = projb[n];
      #pragma unroll
      for (int mt = 0; mt < 4; ++mt) {
        #pragma unroll
        for (int r = 0; r < 4; ++r) {
          int m = mt*16 + quad*4 + r;
          if (m < 49) {
            int rr = m / 7, cc = m - rr * 7;
            int si = wi*7 + rr + 3; if (si >= 56) si -= 56;
            int sj = wj*7 + cc + 3; if (sj >= 56) sj -= 56;
            int o = (b*3136 + si*56 + sj) * 128 + n;
            x2[o] = acc[mt][nt][r] + pbv + x[o];
          }
        }
      }
    }
  }
}

// ---------------- Kernel B: LN2 + MLP(fast gelu) + residual, 2-chunk hidden ----------------
__global__ __launch_bounds__(256) void mlp_kernel(
    const float* x2,            // aliases out
    const float* __restrict__ n2g, const float* __restrict__ n2b,
    const __hip_bfloat16* __restrict__ w1b, const float* __restrict__ b1,
    const __hip_bfloat16* __restrict__ w2b, const float* __restrict__ b2,
    float* out)
{
  __shared__ alignas(16) __hip_bfloat16 lnb[32][136];   // 8704 B
  __shared__ alignas(16) __hip_bfloat16 hb[32][264];    // 16896 B (one 256-wide j chunk)
  const int tid = threadIdx.x, wave = tid >> 6, lane = tid & 63;
  const int l15 = lane & 15, quad = lane >> 4;
  const int tok0 = blockIdx.x * 32;

  // ---- LN2: all 16 global loads issued up-front, 8 independent reduction chains ----
  {
    float va[8], vb[8];
    const float* base = x2 + tok0 * 128;
    #pragma unroll
    for (int i = 0; i < 8; ++i) {
      int t = wave + i*4;
      va[i] = base[t*128 + lane];
      vb[i] = base[t*128 + lane + 64];
    }
    float g0 = n2g[lane], g1 = n2g[lane+64], e0 = n2b[lane], e1 = n2b[lane+64];
    #pragma unroll
    for (int i = 0; i < 8; ++i) {
      int t = wave + i*4;
      float s = va[i] + vb[i], sq = va[i]*va[i] + vb[i]*vb[i];
      #pragma unroll
      for (int off = 32; off > 0; off >>= 1) {
        s  += __shfl_xor(s,  off);
        sq += __shfl_xor(sq, off);
      }
      float mean = s * 0.0078125f;
      float var  = sq * 0.0078125f - mean*mean;
      float rstd = rsqrtf(var + 1e-5f);
      lnb[t][lane]    = __float2bfloat16((va[i]-mean)*rstd*g0 + e0);
      lnb[t][lane+64] = __float2bfloat16((vb[i]-mean)*rstd*g1 + e1);
    }
  }
  __syncthreads();

  f32x4 acc2[2][2] = {};     // GEMM2 accumulator, persists across chunks
  #pragma unroll
  for (int chunk = 0; chunk < 2; ++chunk) {
    // ---- GEMM1 chunk: wave covers j in [chunk*256 + wave*64, +64), D[j][m] swapped ----
    {
      const int jbl = wave * 64;                // chunk-local j base
      const int jbg = chunk*256 + jbl;          // global j base
      f32x4 acc1[4][2] = {};
      #pragma unroll
      for (int ks = 0; ks < 4; ++ks) {
        short8 lf[2];
        #pragma unroll
        for (int mt = 0; mt < 2; ++mt)
          lf[mt] = *(const short8*)(&lnb[mt*16 + l15][ks*32 + quad*8]);
        #pragma unroll
        for (int jt = 0; jt < 4; ++jt) {
          short8 wf = *(const short8*)(w1b + (jbg + jt*16 + l15)*128 + ks*32 + quad*8);
          #pragma unroll
          for (int mt = 0; mt < 2; ++mt)
            acc1[jt][mt] = __builtin_amdgcn_mfma_f32_16x16x32_bf16(wf, lf[mt], acc1[jt][mt], 0, 0, 0);
        }
      }
      #pragma unroll
      for (int jt = 0; jt < 4; ++jt) {
        int j0l = jbl + jt*16 + quad*4;         // chunk-local
        float bb[4];
        #pragma unroll
        for (int r = 0; r < 4; ++r) bb[r] = b1[chunk*256 + j0l + r];
        #pragma unroll
        for (int mt = 0; mt < 2; ++mt) {
          int m = mt*16 + l15;
          short4v pk;
          #pragma unroll
          for (int r = 0; r < 4; ++r) pk[r] = f2bs(gelu_f(acc1[jt][mt][r] + bb[r]));
          *(short4v*)(&hb[m][j0l]) = pk;
        }
      }
    }
    __syncthreads();   // hb chunk ready

    // ---- GEMM2 partial: k in [chunk*256, +256), D[m][f]; wave covers f in [wave*32, +32) ----
    {
      const int fb2 = wave * 32;
      #pragma unroll
      for (int ks = 0; ks < 8; ++ks) {
        short8 af[2];
        #pragma unroll
        for (int mt = 0; mt < 2; ++mt)
          af[mt] = *(const short8*)(&hb[mt*16 + l15][ks*32 + quad*8]);
        #pragma unroll
        for (int nt = 0; nt < 2; ++nt) {
          short8 bf = *(const short8*)(w2b + (fb2 + nt*16 + l15)*512 + chunk*256 + ks*32 + quad*8);
          #pragma unroll
          for (int mt = 0; mt < 2; ++mt)
            acc2[mt][nt] = __builtin_amdgcn_mfma_f32_16x16x32_bf16(af[mt], bf, acc2[mt][nt], 0, 0, 0);
        }
      }
    }
    if (chunk == 0) __syncthreads();   // hb consumed, safe to overwrite
  }

  // ---- epilogue: bias + residual ----
  {
    const int fb2 = wave * 32;
    #pragma unroll
    for (int nt = 0; nt < 2; ++nt) {
      int f = fb2 + nt*16 + l15;
      float bb = b2[f];
      #pragma unroll
      for (int mt = 0; mt < 2; ++mt) {
        #pragma unroll
        for (int r = 0; r < 4; ++r) {
          int m = mt*16 + quad*4 + r;
          int o = (tok0 + m)*128 + f;
          out[o] = acc2[mt][nt][r] + bb + x2[o];
        }
      }
    }
  }
}

extern "C" void kernel_launch(void* const* d_in, const int* in_sizes, int n_in,
                              void* d_out, int out_size, void* d_ws, size_t ws_size,
                              hipStream_t stream) {
  const float* x     = (const float*)d_in[0];
  const float* n1g   = (const float*)d_in[3];
  const float* n1b   = (const float*)d_in[4];
  const float* qkvw  = (const float*)d_in[5];
  const float* qkvb  = (const float*)d_in[6];
  const float* tab   = (const float*)d_in[7];
  const int*   ridx  = (const int*)d_in[8];
  const float* projw = (const float*)d_in[9];
  const float* projb = (const float*)d_in[10];
  const float* n2g   = (const float*)d_in[11];
  const float* n2b   = (const float*)d_in[12];
  const float* w1    = (const float*)d_in[13];
  const float* b1    = (const float*)d_in[14];
  const float* w2    = (const float*)d_in[15];
  const float* b2    = (const float*)d_in[16];
  float* outp = (float*)d_out;

  __hip_bfloat16* wsb = (__hip_bfloat16*)d_ws;
  float* biasT = (float*)((char*)d_ws + BIAS_BYTE_OFF);

  hipLaunchKernelGGL(conv_kernel, dim3(832), dim3(256), 0, stream,
                     qkvw, projw, w1, w2, tab, ridx, wsb, biasT);
  hipLaunchKernelGGL(attn_kernel, dim3(NWIN), dim3(256), 0, stream,
                     x, n1g, n1b, wsb + QKVW_OFF, qkvb, biasT, wsb + PROJW_OFF, projb, outp);
  hipLaunchKernelGGL(mlp_kernel, dim3(TOK/32), dim3(256), 0, stream,
                     outp, n2g, n2b, wsb + W1_OFF, b1, wsb + W2_OFF, b2, outp);
}